// Round 14
// baseline (202.338 us; speedup 1.0000x reference)
//
#include <hip/hip_runtime.h>
#include <stdint.h>
#include <stddef.h>

typedef __bf16 bf16;
typedef uint32_t u32;
typedef __attribute__((ext_vector_type(8))) __bf16 bf16x8;
typedef __attribute__((ext_vector_type(4))) __bf16 bf16x4;
typedef __attribute__((ext_vector_type(4))) float f32x4;
typedef __attribute__((ext_vector_type(16))) float f32x16;
typedef __attribute__((ext_vector_type(8))) unsigned short u16x8;
typedef __attribute__((ext_vector_type(4))) u32 u32x4;

// -------- async global->LDS (16B) --------
__device__ __forceinline__ void gload_lds16(const void* g, void* l) {
  __builtin_amdgcn_global_load_lds(
      (const __attribute__((address_space(1))) unsigned int*)g,
      (__attribute__((address_space(3))) unsigned int*)l, 16, 0, 0);
}

__device__ __forceinline__ float fast_exp2(float x) {
#if __has_builtin(__builtin_amdgcn_exp2f)
  return __builtin_amdgcn_exp2f(x);
#else
  float r; asm("v_exp_f32 %0, %1" : "=v"(r) : "v"(x)); return r;
#endif
}

__device__ __forceinline__ u32 cvtpk_bf16(float lo, float hi_) {
  u32 r;
  asm("v_cvt_pk_bf16_f32 %0, %1, %2" : "=v"(r) : "v"(lo), "v"(hi_));
  return r;
}

// swap: a[32:63] <-> b[0:31]  (ONLY safe with distinct-origin a,b values)
__device__ __forceinline__ void pl32swap(u32& a, u32& b) {
  asm("v_permlane32_swap_b32 %0, %1" : "+v"(a), "+&v"(b));
}

// cross-half (lane ^ 32) reduce — DS shuffle (bulletproof)
__device__ __forceinline__ float xhalf_max(float v) {
  return fmaxf(v, __shfl_xor(v, 32, 64));
}
__device__ __forceinline__ float xhalf_sum(float v) {
  return v + __shfl_xor(v, 32, 64);
}

__device__ __forceinline__ float max3f(float a, float b, float c) {
  return fmaxf(fmaxf(a, b), c);   // clang fuses to v_max3_f32
}

// ============ prep: transpose+cvt w_qkv, w_out (x-cvt folded into GEMM) ============
__global__ void prep_kernel(const float* __restrict__ w_qkv, bf16* __restrict__ wqkvT,
                            const float* __restrict__ w_out, bf16* __restrict__ woutT) {
  __shared__ __align__(16) bf16 t[64][65];
  const int bx = blockIdx.x;
  const float* in; bf16* outp; int K_, N_, nb, kb;
  if (bx < 768) {
    in = w_qkv; outp = wqkvT; K_ = 1024; N_ = 3072;
    nb = (bx % 48) * 64; kb = (bx / 48) * 64;
  } else {
    int b3 = bx - 768;
    in = w_out; outp = woutT; K_ = 1024; N_ = 1024;
    nb = (b3 % 16) * 64; kb = (b3 / 16) * 64;
  }
  const int c = threadIdx.x & 63, r0 = (threadIdx.x >> 6) * 16;
#pragma unroll
  for (int i = 0; i < 16; ++i) {
    int rr = r0 + i;
    t[c][rr] = (bf16)in[(size_t)(kb + rr) * N_ + nb + c];
  }
  __syncthreads();
#pragma unroll
  for (int i = 0; i < 16; ++i) {
    int rr = r0 + i;
    outp[(size_t)(nb + rr) * K_ + kb + c] = t[rr][c];
  }
}

// ====== GEMM: C[M,N] = A[M,K] * BT[N,K]^T + bias; BM=128, BN templated ======
// 1-D grid, XCD-chunked swizzle (requires gridDim.x % 8 == 0, consecutive swz
// share the B panel within an XCD). AFP32: A fp32, converted during staging.
#define BM 128
#define BK 64

template <int MODE, int BN_, bool AFP32>
__global__ __launch_bounds__(256) void gemm_bt(
    const void* __restrict__ Araw, const bf16* __restrict__ BT,
    const float* __restrict__ bias, void* __restrict__ Cout,
    int M, int N, int K, float qscale, int qcols) {
  __shared__ __align__(16) bf16 As[BM * BK];
  __shared__ __align__(16) bf16 Bs[BN_ * BK];
  const int tid = threadIdx.x;
  const int lane = tid & 63;
  const int w = tid >> 6;
  const int wm = (w >> 1) * 64;
  const int wn = (w & 1) * (BN_ / 2);
  // XCD-chunked swizzle: chunk = NB/8 consecutive swz per XCD; m fastest
  const int nb_ = gridDim.x;
  const int bid = blockIdx.x;
  const int swz = (bid & 7) * (nb_ >> 3) + (bid >> 3);
  const int mtiles = M / BM;
  const int m0 = (swz % mtiles) * BM;
  const int n0 = (swz / mtiles) * BN_;
  const int r = lane & 15, g = lane >> 4;
  constexpr int NF = BN_ / 32;

  f32x4 acc[4][NF] = {};

  for (int k0 = 0; k0 < K; k0 += BK) {
    __syncthreads();
    // B tile first (async gload_lds), so A's reg-staging work hides its latency
#pragma unroll
    for (int i = 0; i < BN_ / 32; ++i) {
      int id = tid + i * 256;
      int row = id >> 3, c = id & 7;
      int sc = c ^ (row & 7);
      gload_lds16(BT + (size_t)(n0 + row) * K + k0 + sc * 8, Bs + id * 8);
    }
#pragma unroll
    for (int i = 0; i < 4; ++i) {       // A tile: 128x64
      int id = tid + i * 256;
      int row = id >> 3, c = id & 7;
      int sc = c ^ (row & 7);
      if constexpr (AFP32) {
        const float* p = (const float*)Araw + (size_t)(m0 + row) * K + k0 + sc * 8;
        float4 v0 = *(const float4*)p;
        float4 v1 = *(const float4*)(p + 4);
        u32x4 pk;
        pk[0] = cvtpk_bf16(v0.x, v0.y);
        pk[1] = cvtpk_bf16(v0.z, v0.w);
        pk[2] = cvtpk_bf16(v1.x, v1.y);
        pk[3] = cvtpk_bf16(v1.z, v1.w);
        *(u32x4*)(As + id * 8) = pk;
      } else {
        gload_lds16((const bf16*)Araw + (size_t)(m0 + row) * K + k0 + sc * 8, As + id * 8);
      }
    }
    __syncthreads();
#pragma unroll
    for (int s = 0; s < 2; ++s) {
      bf16x8 fa[4], fb[NF];
#pragma unroll
      for (int i = 0; i < 4; ++i) {
        int arow = wm + i * 16 + r;
        fa[i] = *(const bf16x8*)(As + arow * 64 + (((s * 4 + g) ^ (arow & 7)) << 3));
      }
#pragma unroll
      for (int j = 0; j < NF; ++j) {
        int brow = wn + j * 16 + r;
        fb[j] = *(const bf16x8*)(Bs + brow * 64 + (((s * 4 + g) ^ (brow & 7)) << 3));
      }
#pragma unroll
      for (int i = 0; i < 4; ++i)
#pragma unroll
        for (int j = 0; j < NF; ++j)
          acc[i][j] = __builtin_amdgcn_mfma_f32_16x16x32_bf16(fa[i], fb[j], acc[i][j], 0, 0, 0);
    }
  }

#pragma unroll
  for (int i = 0; i < 4; ++i) {
#pragma unroll
    for (int j = 0; j < NF; ++j) {
      int col = n0 + wn + j * 16 + r;
      float b = bias[col];
      float sc = (MODE == 0 && col < qcols) ? qscale : 1.0f;
#pragma unroll
      for (int rr = 0; rr < 4; ++rr) {
        int row = m0 + wm + i * 16 + g * 4 + rr;
        float v = (acc[i][j][rr] + b) * sc;
        if (MODE == 0)
          ((bf16*)Cout)[(size_t)row * N + col] = (bf16)v;
        else
          ((float*)Cout)[(size_t)row * N + col] = v;
      }
    }
  }
}

// ===== fused flash attention (proven body): 8 waves, kv-split x2 =====
#define LDQ 3072
#define VSTR 68   // LDS row stride (bf16): 136B -> 34 words == 2 mod 32 banks

__global__ __launch_bounds__(512, 4) void attn_fwd6(const bf16* __restrict__ qkv,
                                                    bf16* __restrict__ out) {
  __shared__ __align__(16) bf16 Kl[2][2][64 * VSTR];  // [buf][half][kv*VSTR+d]
  __shared__ __align__(16) bf16 Vt[2][2][64 * VSTR];  // [buf][half][d*VSTR+kv]
  __shared__ float ml[4][32][2];

  const int tid = threadIdx.x, lane = tid & 63, w = tid >> 6;
  const int hi = lane >> 5, q = lane & 31;
  const int qt = w & 3, half = w >> 2;

  const int bid = blockIdx.x;
  const int swz = (bid & 7) * 64 + (bid >> 3);
  const int h = swz >> 5, qb = swz & 31;
  const int q0 = qb * 128 + qt * 32;

  const bf16* Qg = qkv + h * 64;
  const bf16* Kg = qkv + 1024 + h * 64;
  const bf16* Vg = qkv + 2048 + h * 64;

  bf16x8 fq[4];
  {
    const bf16* qp = Qg + (size_t)(q0 + q) * LDQ + hi * 8;
#pragma unroll
    for (int st = 0; st < 4; ++st) fq[st] = *(const bf16x8*)(qp + st * 16);
  }

  const int khalf = tid >> 8;
  const int tk = tid & 255;
  const int krow = tk & 63, kq = tk >> 6;
  const int vhalf = tid >> 8;
  const int tv = tid & 255;
  const int kvp = tv & 31, dgh = tv >> 5;
  const int kv0 = kvp * 2;

  bf16x8 kstg0, kstg1;
  bf16x8 vreg0, vreg1;

  auto load_k = [&](int it) {
    const bf16* kp = Kg + (size_t)(khalf * 2048 + it * 64 + krow) * LDQ + kq * 16;
    kstg0 = *(const bf16x8*)kp;
    kstg1 = *(const bf16x8*)(kp + 8);
  };
  auto stage_k = [&](int buf) {
    bf16* base = &Kl[buf][khalf][krow * VSTR + kq * 16];
    bf16x4 a0 = __builtin_shufflevector(kstg0, kstg0, 0, 1, 2, 3);
    bf16x4 a1 = __builtin_shufflevector(kstg0, kstg0, 4, 5, 6, 7);
    bf16x4 a2 = __builtin_shufflevector(kstg1, kstg1, 0, 1, 2, 3);
    bf16x4 a3 = __builtin_shufflevector(kstg1, kstg1, 4, 5, 6, 7);
    *(bf16x4*)(base + 0)  = a0;
    *(bf16x4*)(base + 4)  = a1;
    *(bf16x4*)(base + 8)  = a2;
    *(bf16x4*)(base + 12) = a3;
  };
  auto load_v = [&](int it) {
    const bf16* vp = Vg + (size_t)(vhalf * 2048 + it * 64 + kv0) * LDQ + dgh * 8;
    vreg0 = *(const bf16x8*)vp;
    vreg1 = *(const bf16x8*)(vp + LDQ);
  };
  auto stage_v = [&](int buf) {
    bf16* base = &Vt[buf][vhalf][0];
    u16x8 lo = __builtin_bit_cast(u16x8, vreg0);
    u16x8 hb = __builtin_bit_cast(u16x8, vreg1);
#pragma unroll
    for (int jj = 0; jj < 8; ++jj) {
      int d = dgh * 8 + jj;
      u32 pk = (u32)lo[jj] | ((u32)hb[jj] << 16);
      *(u32*)(base + d * VSTR + kv0) = pk;
    }
  };
  auto ld8 = [&](const bf16* tb, int row, int c8) -> bf16x8 {
    const bf16* p = tb + row * VSTR + c8 * 8;
    bf16x4 lo = *(const bf16x4*)p;
    bf16x4 hb = *(const bf16x4*)(p + 4);
    return __builtin_shufflevector(lo, hb, 0, 1, 2, 3, 4, 5, 6, 7);
  };

  load_k(0);
  load_v(0);
  stage_k(0);
  stage_v(0);

  f32x16 o0 = {}, o1 = {};
  float m_run = -1e30f, l_run = 0.f;
  __syncthreads();

  for (int it = 0; it < 32; ++it) {
    const int cur = it & 1, nxt = cur ^ 1;
    const bool pfch = (it < 31);

    if (pfch) { load_k(it + 1); load_v(it + 1); }

    const bf16* kb = &Kl[cur][half][0];
    const bf16* vb = &Vt[cur][half][0];

    f32x16 p0 = {}, p1 = {};
    __builtin_amdgcn_s_setprio(1);
#pragma unroll
    for (int st = 0; st < 4; ++st)
      p0 = __builtin_amdgcn_mfma_f32_32x32x16_bf16(ld8(kb, q, 2 * st + hi), fq[st], p0, 0, 0, 0);
#pragma unroll
    for (int st = 0; st < 4; ++st)
      p1 = __builtin_amdgcn_mfma_f32_32x32x16_bf16(ld8(kb, 32 + q, 2 * st + hi), fq[st], p1, 0, 0, 0);
    __builtin_amdgcn_s_setprio(0);

    // ================= softmax half A (p0) =================
    float a0 = max3f(p0[0], p0[1], p0[2]);
    float a1 = max3f(p0[3], p0[4], p0[5]);
    float a2 = max3f(p0[6], p0[7], p0[8]);
    float a3 = max3f(p0[9], p0[10], p0[11]);
    float a4 = max3f(p0[12], p0[13], p0[14]);
    float mxa = xhalf_max(max3f(max3f(a0, a1, a2), max3f(a3, a4, p0[15]), -1e30f));

    if (__any(mxa > m_run + 8.0f)) {     // defer-max (T13)
      float mnew = fmaxf(m_run, mxa);
      float alpha = fast_exp2(m_run - mnew);
      l_run *= alpha;
#pragma unroll
      for (int i = 0; i < 16; ++i) { o0[i] *= alpha; o1[i] *= alpha; }
      m_run = mnew;
    }
#pragma unroll
    for (int i = 0; i < 16; ++i) p0[i] = fast_exp2(p0[i] - m_run);

    float sa[8];
#pragma unroll
    for (int i = 0; i < 8; ++i) sa[i] = p0[i] + p0[i + 8];
#pragma unroll
    for (int s2 = 4; s2 > 0; s2 >>= 1)
#pragma unroll
      for (int i = 0; i < s2; ++i) sa[i] += sa[i + s2];
    float psum = sa[0];

    u32x4 pb[4];
#pragma unroll
    for (int qd = 0; qd < 2; ++qd) {
      u32 c0 = cvtpk_bf16(p0[qd * 8 + 0], p0[qd * 8 + 1]);
      u32 d0 = cvtpk_bf16(p0[qd * 8 + 4], p0[qd * 8 + 5]);
      u32 c1 = cvtpk_bf16(p0[qd * 8 + 2], p0[qd * 8 + 3]);
      u32 d1 = cvtpk_bf16(p0[qd * 8 + 6], p0[qd * 8 + 7]);
      pl32swap(c0, d0);
      pl32swap(c1, d1);
      pb[qd][0] = c0; pb[qd][1] = c1; pb[qd][2] = d0; pb[qd][3] = d1;
    }

    __builtin_amdgcn_s_setprio(1);
#pragma unroll
    for (int ks = 0; ks < 2; ++ks) {
      bf16x8 pf2 = __builtin_bit_cast(bf16x8, pb[ks]);
      o0 = __builtin_amdgcn_mfma_f32_32x32x16_bf16(ld8(vb, q, 2 * ks + hi), pf2, o0, 0, 0, 0);
      o1 = __builtin_amdgcn_mfma_f32_32x32x16_bf16(ld8(vb, 32 + q, 2 * ks + hi), pf2, o1, 0, 0, 0);
    }
    __builtin_amdgcn_s_setprio(0);

    // ================= softmax half B (p1) =================
    float b0 = max3f(p1[0], p1[1], p1[2]);
    float b1 = max3f(p1[3], p1[4], p1[5]);
    float b2 = max3f(p1[6], p1[7], p1[8]);
    float b3 = max3f(p1[9], p1[10], p1[11]);
    float b4 = max3f(p1[12], p1[13], p1[14]);
    float mxb = xhalf_max(max3f(max3f(b0, b1, b2), max3f(b3, b4, p1[15]), -1e30f));

    if (__any(mxb > m_run + 8.0f)) {
      float mnew = fmaxf(m_run, mxb);
      float alpha = fast_exp2(m_run - mnew);
      l_run *= alpha;
      psum *= alpha;
#pragma unroll
      for (int i = 0; i < 16; ++i) { o0[i] *= alpha; o1[i] *= alpha; }
      m_run = mnew;
    }
#pragma unroll
    for (int i = 0; i < 16; ++i) p1[i] = fast_exp2(p1[i] - m_run);

    float sb[8];
#pragma unroll
    for (int i = 0; i < 8; ++i) sb[i] = p1[i] + p1[i + 8];
#pragma unroll
    for (int s2 = 4; s2 > 0; s2 >>= 1)
#pragma unroll
      for (int i = 0; i < s2; ++i) sb[i] += sb[i + s2];

    l_run += xhalf_sum(psum + sb[0]);

#pragma unroll
    for (int qd = 0; qd < 2; ++qd) {
      u32 c0 = cvtpk_bf16(p1[qd * 8 + 0], p1[qd * 8 + 1]);
      u32 d0 = cvtpk_bf16(p1[qd * 8 + 4], p1[qd * 8 + 5]);
      u32 c1 = cvtpk_bf16(p1[qd * 8 + 2], p1[qd * 8 + 3]);
      u32 d1 = cvtpk_bf16(p1[qd * 8 + 6], p1[qd * 8 + 7]);
      pl32swap(c0, d0);
      pl32swap(c1, d1);
      pb[2 + qd][0] = c0; pb[2 + qd][1] = c1; pb[2 + qd][2] = d0; pb[2 + qd][3] = d1;
    }

    __builtin_amdgcn_s_setprio(1);
#pragma unroll
    for (int ks = 2; ks < 4; ++ks) {
      bf16x8 pf2 = __builtin_bit_cast(bf16x8, pb[ks]);
      o0 = __builtin_amdgcn_mfma_f32_32x32x16_bf16(ld8(vb, q, 2 * ks + hi), pf2, o0, 0, 0, 0);
      o1 = __builtin_amdgcn_mfma_f32_32x32x16_bf16(ld8(vb, 32 + q, 2 * ks + hi), pf2, o1, 0, 0, 0);
    }
    __builtin_amdgcn_s_setprio(0);

    if (pfch) { stage_k(nxt); stage_v(nxt); }
    __syncthreads();
  }

  // ---- combine kv-halves through LDS, normalize, store ----
  float* comb = (float*)&Kl[0][0][0];
  if (half == 1) {
    float* dst = comb + qt * 2048 + lane * 32;
#pragma unroll
    for (int c = 0; c < 8; ++c) {
      f32x4 v;
      if (c < 4) { v[0] = o0[c*4+0]; v[1] = o0[c*4+1]; v[2] = o0[c*4+2]; v[3] = o0[c*4+3]; }
      else       { v[0] = o1[(c-4)*4+0]; v[1] = o1[(c-4)*4+1]; v[2] = o1[(c-4)*4+2]; v[3] = o1[(c-4)*4+3]; }
      *(f32x4*)(dst + c * 4) = v;
    }
    if (hi == 0) { ml[qt][q][0] = m_run; ml[qt][q][1] = l_run; }
  }
  __syncthreads();
  if (half == 0) {
    const float* src = comb + qt * 2048 + lane * 32;
    float mB = ml[qt][q][0], lB = ml[qt][q][1];
    float m = fmaxf(m_run, mB);
    float wA = fast_exp2(m_run - m), wB = fast_exp2(mB - m);
    float linv = 1.0f / (l_run * wA + lB * wB);
    wA *= linv; wB *= linv;
    bf16* op = out + (size_t)(q0 + q) * 1024 + h * 64;
#pragma unroll
    for (int c = 0; c < 8; ++c) {
      f32x4 ob = *(const f32x4*)(src + c * 4);
      float e0, e1, e2, e3;
      if (c < 4) { e0 = o0[c*4+0]; e1 = o0[c*4+1]; e2 = o0[c*4+2]; e3 = o0[c*4+3]; }
      else       { e0 = o1[(c-4)*4+0]; e1 = o1[(c-4)*4+1]; e2 = o1[(c-4)*4+2]; e3 = o1[(c-4)*4+3]; }
      e0 = e0 * wA + ob[0] * wB;
      e1 = e1 * wA + ob[1] * wB;
      e2 = e2 * wA + ob[2] * wB;
      e3 = e3 * wA + ob[3] * wB;
      int db = c >> 2, rg = c & 3;
      int dbase = db * 32 + rg * 8 + hi * 4;
      uint2 stv;
      stv.x = cvtpk_bf16(e0, e1);
      stv.y = cvtpk_bf16(e2, e3);
      *(uint2*)(op + dbase) = stv;
    }
  }
}

// ================= launcher =================
extern "C" void kernel_launch(void* const* d_in, const int* in_sizes, int n_in,
                              void* d_out, int out_size, void* d_ws, size_t ws_size,
                              hipStream_t stream) {
  const float* x     = (const float*)d_in[0];
  const float* w_qkv = (const float*)d_in[1];
  const float* b_qkv = (const float*)d_in[2];
  const float* w_out = (const float*)d_in[3];
  const float* b_out = (const float*)d_in[4];
  float* outp = (float*)d_out;

  char* ws = (char*)d_ws;
  bf16* qkv   = (bf16*)(ws);                          // [4096][3072]  24 MB
  bf16* xbf   = (bf16*)(ws + 24u * 1024 * 1024);      // [4096][1024]   8 MB (attn out)
  bf16* wqkvT = (bf16*)(ws + 32u * 1024 * 1024);      // [3072][1024]   6 MB
  bf16* woutT = (bf16*)(ws + 38u * 1024 * 1024);      // [1024][1024]   2 MB

  prep_kernel<<<1024, 256, 0, stream>>>(w_qkv, wqkvT, w_out, woutT);

  // QKV: BN=192 -> 32x16 tiles = 512 blocks = 2/CU exact, XCD-chunked
  gemm_bt<0, 192, true><<<512, 256, 0, stream>>>(x, wqkvT, b_qkv, qkv,
                                                 4096, 3072, 1024,
                                                 0.125f * 1.44269504088896f, 1024);

  attn_fwd6<<<512, 512, 0, stream>>>(qkv, xbf);

  // out-proj: BN=64 -> 32x16 tiles = 512 blocks = 2/CU, XCD-chunked
  gemm_bt<1, 64, false><<<512, 256, 0, stream>>>(xbf, woutT, b_out, outp,
                                                 4096, 1024, 1024, 1.0f, 0);
}

// Round 15
// 164.558 us; speedup vs baseline: 1.2296x; 1.2296x over previous
//
#include <hip/hip_runtime.h>
#include <stdint.h>
#include <stddef.h>

typedef __bf16 bf16;
typedef uint32_t u32;
typedef __attribute__((ext_vector_type(8))) __bf16 bf16x8;
typedef __attribute__((ext_vector_type(4))) __bf16 bf16x4;
typedef __attribute__((ext_vector_type(4))) float f32x4;
typedef __attribute__((ext_vector_type(16))) float f32x16;
typedef __attribute__((ext_vector_type(8))) unsigned short u16x8;
typedef __attribute__((ext_vector_type(4))) u32 u32x4;

// -------- async global->LDS (16B) --------
__device__ __forceinline__ void gload_lds16(const void* g, void* l) {
  __builtin_amdgcn_global_load_lds(
      (const __attribute__((address_space(1))) unsigned int*)g,
      (__attribute__((address_space(3))) unsigned int*)l, 16, 0, 0);
}

__device__ __forceinline__ float fast_exp2(float x) {
#if __has_builtin(__builtin_amdgcn_exp2f)
  return __builtin_amdgcn_exp2f(x);
#else
  float r; asm("v_exp_f32 %0, %1" : "=v"(r) : "v"(x)); return r;
#endif
}

__device__ __forceinline__ u32 cvtpk_bf16(float lo, float hi_) {
  u32 r;
  asm("v_cvt_pk_bf16_f32 %0, %1, %2" : "=v"(r) : "v"(lo), "v"(hi_));
  return r;
}

// swap: a[32:63] <-> b[0:31]  (ONLY safe with distinct-origin a,b values)
__device__ __forceinline__ void pl32swap(u32& a, u32& b) {
  asm("v_permlane32_swap_b32 %0, %1" : "+v"(a), "+&v"(b));
}

// cross-half (lane ^ 32) reduce — DS shuffle (bulletproof)
__device__ __forceinline__ float xhalf_max(float v) {
  return fmaxf(v, __shfl_xor(v, 32, 64));
}
__device__ __forceinline__ float xhalf_sum(float v) {
  return v + __shfl_xor(v, 32, 64);
}

__device__ __forceinline__ float max3f(float a, float b, float c) {
  return fmaxf(fmaxf(a, b), c);   // clang fuses to v_max3_f32
}

// ============ prep: transpose+cvt w_qkv, w_out (x-cvt folded into GEMM) ============
// blocks [0,768):     w_qkv [1024][3072] -> wqkvT [3072][1024] bf16
// blocks [768,1024):  w_out [1024][1024] -> woutT [1024][1024] bf16
__global__ void prep_kernel(const float* __restrict__ w_qkv, bf16* __restrict__ wqkvT,
                            const float* __restrict__ w_out, bf16* __restrict__ woutT) {
  __shared__ __align__(16) bf16 t[64][65];
  const int bx = blockIdx.x;
  const float* in; bf16* outp; int K_, N_, nb, kb;
  if (bx < 768) {
    in = w_qkv; outp = wqkvT; K_ = 1024; N_ = 3072;
    nb = (bx % 48) * 64; kb = (bx / 48) * 64;
  } else {
    int b3 = bx - 768;
    in = w_out; outp = woutT; K_ = 1024; N_ = 1024;
    nb = (b3 % 16) * 64; kb = (b3 / 16) * 64;
  }
  const int c = threadIdx.x & 63, r0 = (threadIdx.x >> 6) * 16;
#pragma unroll
  for (int i = 0; i < 16; ++i) {
    int rr = r0 + i;
    t[c][rr] = (bf16)in[(size_t)(kb + rr) * N_ + nb + c];
  }
  __syncthreads();
#pragma unroll
  for (int i = 0; i < 16; ++i) {
    int rr = r0 + i;
    outp[(size_t)(nb + rr) * K_ + kb + c] = t[rr][c];
  }
}

// ====== GEMM: C[M,N] = A[M,K] * BT[N,K]^T + bias; BM=128, BN templated ======
// AFP32: A is fp32, reg-staged + converted to bf16 in LDS (same swizzled layout).
// MODE 0: bf16 output with qscale on col<qcols; MODE 1: fp32 output.
#define BM 128
#define BK 64

template <int MODE, int BN_, bool AFP32>
__global__ __launch_bounds__(256) void gemm_bt(
    const void* __restrict__ Araw, const bf16* __restrict__ BT,
    const float* __restrict__ bias, void* __restrict__ Cout,
    int M, int N, int K, float qscale, int qcols) {
  __shared__ __align__(16) bf16 As[BM * BK];
  __shared__ __align__(16) bf16 Bs[BN_ * BK];
  const int tid = threadIdx.x;
  const int lane = tid & 63;
  const int w = tid >> 6;
  const int wm = (w >> 1) * 64;
  const int wn = (w & 1) * (BN_ / 2);
  const int m0 = blockIdx.x * BM;
  const int n0 = blockIdx.y * BN_;
  const int r = lane & 15, g = lane >> 4;
  constexpr int NF = BN_ / 32;

  f32x4 acc[4][NF] = {};

  for (int k0 = 0; k0 < K; k0 += BK) {
    __syncthreads();
    // B tile first (async gload_lds), so A's reg-staging work hides its latency
#pragma unroll
    for (int i = 0; i < BN_ / 32; ++i) {
      int id = tid + i * 256;
      int row = id >> 3, c = id & 7;
      int sc = c ^ (row & 7);
      gload_lds16(BT + (size_t)(n0 + row) * K + k0 + sc * 8, Bs + id * 8);
    }
#pragma unroll
    for (int i = 0; i < 4; ++i) {       // A tile: 128x64
      int id = tid + i * 256;
      int row = id >> 3, c = id & 7;
      int sc = c ^ (row & 7);
      if constexpr (AFP32) {
        const float* p = (const float*)Araw + (size_t)(m0 + row) * K + k0 + sc * 8;
        float4 v0 = *(const float4*)p;
        float4 v1 = *(const float4*)(p + 4);
        u32x4 pk;
        pk[0] = cvtpk_bf16(v0.x, v0.y);
        pk[1] = cvtpk_bf16(v0.z, v0.w);
        pk[2] = cvtpk_bf16(v1.x, v1.y);
        pk[3] = cvtpk_bf16(v1.z, v1.w);
        *(u32x4*)(As + id * 8) = pk;
      } else {
        gload_lds16((const bf16*)Araw + (size_t)(m0 + row) * K + k0 + sc * 8, As + id * 8);
      }
    }
    __syncthreads();
#pragma unroll
    for (int s = 0; s < 2; ++s) {
      bf16x8 fa[4], fb[NF];
#pragma unroll
      for (int i = 0; i < 4; ++i) {
        int arow = wm + i * 16 + r;
        fa[i] = *(const bf16x8*)(As + arow * 64 + (((s * 4 + g) ^ (arow & 7)) << 3));
      }
#pragma unroll
      for (int j = 0; j < NF; ++j) {
        int brow = wn + j * 16 + r;
        fb[j] = *(const bf16x8*)(Bs + brow * 64 + (((s * 4 + g) ^ (brow & 7)) << 3));
      }
#pragma unroll
      for (int i = 0; i < 4; ++i)
#pragma unroll
        for (int j = 0; j < NF; ++j)
          acc[i][j] = __builtin_amdgcn_mfma_f32_16x16x32_bf16(fa[i], fb[j], acc[i][j], 0, 0, 0);
    }
  }

#pragma unroll
  for (int i = 0; i < 4; ++i) {
#pragma unroll
    for (int j = 0; j < NF; ++j) {
      int col = n0 + wn + j * 16 + r;
      float b = bias[col];
      float sc = (MODE == 0 && col < qcols) ? qscale : 1.0f;
#pragma unroll
      for (int rr = 0; rr < 4; ++rr) {
        int row = m0 + wm + i * 16 + g * 4 + rr;
        float v = (acc[i][j][rr] + b) * sc;
        if (MODE == 0)
          ((bf16*)Cout)[(size_t)row * N + col] = (bf16)v;
        else
          ((float*)Cout)[(size_t)row * N + col] = v;
      }
    }
  }
}

// ===== fused flash attention (proven body): 8 waves, kv-split x2 =====
// qkv: bf16 [4096][3072]; Q pre-scaled by 0.125*log2e. out: bf16 [4096][1024].
// Block: 8 waves = {4 q-tiles x 32 rows} x {2 kv-halves}. Grid 512 (1-D, XCD-chunked).
#define LDQ 3072
#define VSTR 68   // LDS row stride (bf16): 136B -> 34 words == 2 mod 32 banks

__global__ __launch_bounds__(512, 4) void attn_fwd6(const bf16* __restrict__ qkv,
                                                    bf16* __restrict__ out) {
  __shared__ __align__(16) bf16 Kl[2][2][64 * VSTR];  // [buf][half][kv*VSTR+d]
  __shared__ __align__(16) bf16 Vt[2][2][64 * VSTR];  // [buf][half][d*VSTR+kv]
  __shared__ float ml[4][32][2];

  const int tid = threadIdx.x, lane = tid & 63, w = tid >> 6;
  const int hi = lane >> 5, q = lane & 31;
  const int qt = w & 3, half = w >> 2;

  // XCD-chunked swizzle: 512 blocks, 8 XCDs -> 64 consecutive per XCD (2 heads)
  const int bid = blockIdx.x;
  const int swz = (bid & 7) * 64 + (bid >> 3);
  const int h = swz >> 5, qb = swz & 31;
  const int q0 = qb * 128 + qt * 32;

  const bf16* Qg = qkv + h * 64;
  const bf16* Kg = qkv + 1024 + h * 64;
  const bf16* Vg = qkv + 2048 + h * 64;

  // Q B-frags: col=q, k = st*16 + hi*8 + j (loop-invariant)
  bf16x8 fq[4];
  {
    const bf16* qp = Qg + (size_t)(q0 + q) * LDQ + hi * 8;
#pragma unroll
    for (int st = 0; st < 4; ++st) fq[st] = *(const bf16x8*)(qp + st * 16);
  }

  // K staging: 256 threads per half; row = t&63 (wave-linear), quarter = wave
  const int khalf = tid >> 8;
  const int tk = tid & 255;
  const int krow = tk & 63, kq = tk >> 6;
  // V staging: 256 threads per half
  const int vhalf = tid >> 8;
  const int tv = tid & 255;
  const int kvp = tv & 31, dgh = tv >> 5;
  const int kv0 = kvp * 2;

  bf16x8 kstg0, kstg1;
  bf16x8 vreg0, vreg1;

  auto load_k = [&](int it) {
    const bf16* kp = Kg + (size_t)(khalf * 2048 + it * 64 + krow) * LDQ + kq * 16;
    kstg0 = *(const bf16x8*)kp;
    kstg1 = *(const bf16x8*)(kp + 8);
  };
  auto stage_k = [&](int buf) {
    bf16* base = &Kl[buf][khalf][krow * VSTR + kq * 16];
    bf16x4 a0 = __builtin_shufflevector(kstg0, kstg0, 0, 1, 2, 3);
    bf16x4 a1 = __builtin_shufflevector(kstg0, kstg0, 4, 5, 6, 7);
    bf16x4 a2 = __builtin_shufflevector(kstg1, kstg1, 0, 1, 2, 3);
    bf16x4 a3 = __builtin_shufflevector(kstg1, kstg1, 4, 5, 6, 7);
    *(bf16x4*)(base + 0)  = a0;
    *(bf16x4*)(base + 4)  = a1;
    *(bf16x4*)(base + 8)  = a2;
    *(bf16x4*)(base + 12) = a3;
  };
  auto load_v = [&](int it) {
    const bf16* vp = Vg + (size_t)(vhalf * 2048 + it * 64 + kv0) * LDQ + dgh * 8;
    vreg0 = *(const bf16x8*)vp;
    vreg1 = *(const bf16x8*)(vp + LDQ);
  };
  auto stage_v = [&](int buf) {
    bf16* base = &Vt[buf][vhalf][0];
    u16x8 lo = __builtin_bit_cast(u16x8, vreg0);
    u16x8 hb = __builtin_bit_cast(u16x8, vreg1);
#pragma unroll
    for (int jj = 0; jj < 8; ++jj) {
      int d = dgh * 8 + jj;
      u32 pk = (u32)lo[jj] | ((u32)hb[jj] << 16);
      *(u32*)(base + d * VSTR + kv0) = pk;
    }
  };
  // fragment read from padded tile: row, 8-elem chunk c8 (two b64, bank-spread)
  auto ld8 = [&](const bf16* tb, int row, int c8) -> bf16x8 {
    const bf16* p = tb + row * VSTR + c8 * 8;
    bf16x4 lo = *(const bf16x4*)p;
    bf16x4 hb = *(const bf16x4*)(p + 4);
    return __builtin_shufflevector(lo, hb, 0, 1, 2, 3, 4, 5, 6, 7);
  };

  load_k(0);
  load_v(0);
  stage_k(0);
  stage_v(0);

  f32x16 o0 = {}, o1 = {};
  float m_run = -1e30f, l_run = 0.f;
  __syncthreads();

  for (int it = 0; it < 32; ++it) {
    const int cur = it & 1, nxt = cur ^ 1;
    const bool pfch = (it < 31);

    // prefetch next tiles first: latency hides under full body (T14)
    if (pfch) { load_k(it + 1); load_v(it + 1); }

    const bf16* kb = &Kl[cur][half][0];
    const bf16* vb = &Vt[cur][half][0];

    // ---- S^T = K * Q^T : p0 (kv 0..31) first, then p1 (kv 32..63) ----
    f32x16 p0 = {}, p1 = {};
    __builtin_amdgcn_s_setprio(1);
#pragma unroll
    for (int st = 0; st < 4; ++st)
      p0 = __builtin_amdgcn_mfma_f32_32x32x16_bf16(ld8(kb, q, 2 * st + hi), fq[st], p0, 0, 0, 0);
#pragma unroll
    for (int st = 0; st < 4; ++st)
      p1 = __builtin_amdgcn_mfma_f32_32x32x16_bf16(ld8(kb, 32 + q, 2 * st + hi), fq[st], p1, 0, 0, 0);
    __builtin_amdgcn_s_setprio(0);

    // ================= softmax half A (p0) =================
    float a0 = max3f(p0[0], p0[1], p0[2]);
    float a1 = max3f(p0[3], p0[4], p0[5]);
    float a2 = max3f(p0[6], p0[7], p0[8]);
    float a3 = max3f(p0[9], p0[10], p0[11]);
    float a4 = max3f(p0[12], p0[13], p0[14]);
    float mxa = xhalf_max(max3f(max3f(a0, a1, a2), max3f(a3, a4, p0[15]), -1e30f));

    if (__any(mxa > m_run + 8.0f)) {     // defer-max (T13)
      float mnew = fmaxf(m_run, mxa);
      float alpha = fast_exp2(m_run - mnew);
      l_run *= alpha;
#pragma unroll
      for (int i = 0; i < 16; ++i) { o0[i] *= alpha; o1[i] *= alpha; }
      m_run = mnew;
    }
#pragma unroll
    for (int i = 0; i < 16; ++i) p0[i] = fast_exp2(p0[i] - m_run);

    float sa[8];
#pragma unroll
    for (int i = 0; i < 8; ++i) sa[i] = p0[i] + p0[i + 8];
#pragma unroll
    for (int s2 = 4; s2 > 0; s2 >>= 1)
#pragma unroll
      for (int i = 0; i < s2; ++i) sa[i] += sa[i + s2];
    float psum = sa[0];

    // cvt half A -> pb[0], pb[1]
    u32x4 pb[4];
#pragma unroll
    for (int qd = 0; qd < 2; ++qd) {
      u32 c0 = cvtpk_bf16(p0[qd * 8 + 0], p0[qd * 8 + 1]);
      u32 d0 = cvtpk_bf16(p0[qd * 8 + 4], p0[qd * 8 + 5]);
      u32 c1 = cvtpk_bf16(p0[qd * 8 + 2], p0[qd * 8 + 3]);
      u32 d1 = cvtpk_bf16(p0[qd * 8 + 6], p0[qd * 8 + 7]);
      pl32swap(c0, d0);
      pl32swap(c1, d1);
      pb[qd][0] = c0; pb[qd][1] = c1; pb[qd][2] = d0; pb[qd][3] = d1;
    }

    // ---- PV half A (kv 0..31): MFMA pipe overlaps half-B softmax ----
    __builtin_amdgcn_s_setprio(1);
#pragma unroll
    for (int ks = 0; ks < 2; ++ks) {
      bf16x8 pf2 = __builtin_bit_cast(bf16x8, pb[ks]);
      o0 = __builtin_amdgcn_mfma_f32_32x32x16_bf16(ld8(vb, q, 2 * ks + hi), pf2, o0, 0, 0, 0);
      o1 = __builtin_amdgcn_mfma_f32_32x32x16_bf16(ld8(vb, 32 + q, 2 * ks + hi), pf2, o1, 0, 0, 0);
    }
    __builtin_amdgcn_s_setprio(0);

    // ================= softmax half B (p1) =================
    float b0 = max3f(p1[0], p1[1], p1[2]);
    float b1 = max3f(p1[3], p1[4], p1[5]);
    float b2 = max3f(p1[6], p1[7], p1[8]);
    float b3 = max3f(p1[9], p1[10], p1[11]);
    float b4 = max3f(p1[12], p1[13], p1[14]);
    float mxb = xhalf_max(max3f(max3f(b0, b1, b2), max3f(b3, b4, p1[15]), -1e30f));

    if (__any(mxb > m_run + 8.0f)) {
      float mnew = fmaxf(m_run, mxb);
      float alpha = fast_exp2(m_run - mnew);
      l_run *= alpha;
      psum *= alpha;
#pragma unroll
      for (int i = 0; i < 16; ++i) { o0[i] *= alpha; o1[i] *= alpha; }
      m_run = mnew;
    }
#pragma unroll
    for (int i = 0; i < 16; ++i) p1[i] = fast_exp2(p1[i] - m_run);

    float sb[8];
#pragma unroll
    for (int i = 0; i < 8; ++i) sb[i] = p1[i] + p1[i + 8];
#pragma unroll
    for (int s2 = 4; s2 > 0; s2 >>= 1)
#pragma unroll
      for (int i = 0; i < s2; ++i) sb[i] += sb[i + s2];

    l_run += xhalf_sum(psum + sb[0]);

    // cvt half B -> pb[2], pb[3]
#pragma unroll
    for (int qd = 0; qd < 2; ++qd) {
      u32 c0 = cvtpk_bf16(p1[qd * 8 + 0], p1[qd * 8 + 1]);
      u32 d0 = cvtpk_bf16(p1[qd * 8 + 4], p1[qd * 8 + 5]);
      u32 c1 = cvtpk_bf16(p1[qd * 8 + 2], p1[qd * 8 + 3]);
      u32 d1 = cvtpk_bf16(p1[qd * 8 + 6], p1[qd * 8 + 7]);
      pl32swap(c0, d0);
      pl32swap(c1, d1);
      pb[2 + qd][0] = c0; pb[2 + qd][1] = c1; pb[2 + qd][2] = d0; pb[2 + qd][3] = d1;
    }

    // ---- PV half B (kv 32..63) ----
    __builtin_amdgcn_s_setprio(1);
#pragma unroll
    for (int ks = 2; ks < 4; ++ks) {
      bf16x8 pf2 = __builtin_bit_cast(bf16x8, pb[ks]);
      o0 = __builtin_amdgcn_mfma_f32_32x32x16_bf16(ld8(vb, q, 2 * ks + hi), pf2, o0, 0, 0, 0);
      o1 = __builtin_amdgcn_mfma_f32_32x32x16_bf16(ld8(vb, 32 + q, 2 * ks + hi), pf2, o1, 0, 0, 0);
    }
    __builtin_amdgcn_s_setprio(0);

    // stage next tiles (waits on this iter's global loads)
    if (pfch) { stage_k(nxt); stage_v(nxt); }
    __syncthreads();
  }

  // ---- combine kv-halves through LDS, normalize, store ----
  float* comb = (float*)&Kl[0][0][0];
  if (half == 1) {
    float* dst = comb + qt * 2048 + lane * 32;
#pragma unroll
    for (int c = 0; c < 8; ++c) {
      f32x4 v;
      if (c < 4) { v[0] = o0[c*4+0]; v[1] = o0[c*4+1]; v[2] = o0[c*4+2]; v[3] = o0[c*4+3]; }
      else       { v[0] = o1[(c-4)*4+0]; v[1] = o1[(c-4)*4+1]; v[2] = o1[(c-4)*4+2]; v[3] = o1[(c-4)*4+3]; }
      *(f32x4*)(dst + c * 4) = v;
    }
    if (hi == 0) { ml[qt][q][0] = m_run; ml[qt][q][1] = l_run; }
  }
  __syncthreads();
  if (half == 0) {
    const float* src = comb + qt * 2048 + lane * 32;
    float mB = ml[qt][q][0], lB = ml[qt][q][1];
    float m = fmaxf(m_run, mB);
    float wA = fast_exp2(m_run - m), wB = fast_exp2(mB - m);
    float linv = 1.0f / (l_run * wA + lB * wB);
    wA *= linv; wB *= linv;
    bf16* op = out + (size_t)(q0 + q) * 1024 + h * 64;
#pragma unroll
    for (int c = 0; c < 8; ++c) {
      f32x4 ob = *(const f32x4*)(src + c * 4);
      float e0, e1, e2, e3;
      if (c < 4) { e0 = o0[c*4+0]; e1 = o0[c*4+1]; e2 = o0[c*4+2]; e3 = o0[c*4+3]; }
      else       { e0 = o1[(c-4)*4+0]; e1 = o1[(c-4)*4+1]; e2 = o1[(c-4)*4+2]; e3 = o1[(c-4)*4+3]; }
      e0 = e0 * wA + ob[0] * wB;
      e1 = e1 * wA + ob[1] * wB;
      e2 = e2 * wA + ob[2] * wB;
      e3 = e3 * wA + ob[3] * wB;
      int db = c >> 2, rg = c & 3;
      int dbase = db * 32 + rg * 8 + hi * 4;
      uint2 stv;
      stv.x = cvtpk_bf16(e0, e1);
      stv.y = cvtpk_bf16(e2, e3);
      *(uint2*)(op + dbase) = stv;
    }
  }
}

// ================= launcher =================
extern "C" void kernel_launch(void* const* d_in, const int* in_sizes, int n_in,
                              void* d_out, int out_size, void* d_ws, size_t ws_size,
                              hipStream_t stream) {
  const float* x     = (const float*)d_in[0];
  const float* w_qkv = (const float*)d_in[1];
  const float* b_qkv = (const float*)d_in[2];
  const float* w_out = (const float*)d_in[3];
  const float* b_out = (const float*)d_in[4];
  float* outp = (float*)d_out;

  char* ws = (char*)d_ws;
  bf16* qkv   = (bf16*)(ws);                          // [4096][3072]  24 MB
  bf16* xbf   = (bf16*)(ws + 24u * 1024 * 1024);      // [4096][1024]   8 MB (attn out)
  bf16* wqkvT = (bf16*)(ws + 32u * 1024 * 1024);      // [3072][1024]   6 MB
  bf16* woutT = (bf16*)(ws + 38u * 1024 * 1024);      // [1024][1024]   2 MB

  // prep: weight transposes only (x-cvt folded into QKV GEMM A-staging)
  prep_kernel<<<1024, 256, 0, stream>>>(w_qkv, wqkvT, w_out, woutT);

  // QKV projection: A = x (fp32, converted in-staging); 768 blocks = 3/CU exact
  gemm_bt<0, 128, true><<<dim3(32, 24), 256, 0, stream>>>(x, wqkvT, b_qkv, qkv,
                                                          4096, 3072, 1024,
                                                          0.125f * 1.44269504088896f, 1024);

  attn_fwd6<<<512, 512, 0, stream>>>(qkv, xbf);

  // out-proj: BN=64 -> 32x16 = 512 blocks = 2/CU exact
  gemm_bt<1, 64, false><<<dim3(32, 16), 256, 0, stream>>>(xbf, woutT, b_out, outp,
                                                          4096, 1024, 1024, 1.0f, 0);
}